// Round 1
// baseline (16685.632 us; speedup 1.0000x reference)
//
#include <hip/hip_runtime.h>
#include <hip/hip_bf16.h>

#define TT 2048
#define BB 256
#define II 64
#define HH 128
#define GG 512   // 4*H
#define NHH 512
#define OO 64

// ---------- helpers ----------
__device__ __forceinline__ float sigmoid_f(float x) {
    return 1.f / (1.f + __expf(-x));
}
// overflow-safe tanh: exp of a non-positive argument only
__device__ __forceinline__ float tanh_f(float x) {
    float ax = fabsf(x);
    float e = __expf(-2.f * ax);
    float t = (1.f - e) / (1.f + e);
    return copysignf(t, x);
}
__device__ __forceinline__ float bf2f(unsigned short u) {
    union { float f; unsigned int i; } v; v.i = ((unsigned int)u) << 16; return v.f;
}

// ---------- prep: transpose weights into ws (coalesced [k][g] layouts) ----------
__global__ void prep_kernel(const float* __restrict__ W_ih, const float* __restrict__ W_hh,
                            const float* __restrict__ b_ih, const float* __restrict__ b_hh,
                            const float* __restrict__ W1,   const float* __restrict__ W2,
                            float* __restrict__ WihT, float* __restrict__ WhhT,
                            float* __restrict__ bias, float* __restrict__ W1T,
                            float* __restrict__ W2T)
{
    int tid = blockIdx.x * blockDim.x + threadIdx.x;
    int n = gridDim.x * blockDim.x;
    for (int idx = tid; idx < GG * II; idx += n) {       // W_ih [512,64] -> [64,512]
        int g = idx / II, k = idx % II;
        WihT[k * GG + g] = W_ih[idx];
    }
    for (int idx = tid; idx < GG * HH; idx += n) {       // W_hh [512,128] -> [128,512]
        int g = idx / HH, k = idx % HH;
        WhhT[k * GG + g] = W_hh[idx];
    }
    for (int idx = tid; idx < GG; idx += n)
        bias[idx] = b_ih[idx] + b_hh[idx];
    for (int idx = tid; idx < NHH * HH; idx += n) {      // W1 [512,128] -> [128,512]
        int nn = idx / HH, k = idx % HH;
        W1T[k * NHH + nn] = W1[idx];
    }
    for (int idx = tid; idx < OO * NHH; idx += n) {      // W2 [64,512] -> [512,64]
        int o = idx / NHH, nn = idx % NHH;
        W2T[nn * OO + o] = W2[idx];
    }
}

// ---------- LSTM scan: 64 blocks x 4 batch rows, fp32 recurrence ----------
__global__ __launch_bounds__(512) void lstm_scan_kernel(
    const float* __restrict__ x,
    const float* __restrict__ WihT,
    const float* __restrict__ WhhT,
    const float* __restrict__ bias,
    __hip_bfloat16* __restrict__ hs,
    float* __restrict__ out_tail)   // d_out + T*B*O : [h_n | c_n]
{
    __shared__ float h_lds[4][HH];
    __shared__ float xt[4][II];
    __shared__ float gact[4][GG];

    const int tid = threadIdx.x;
    const int b0 = blockIdx.x * 4;
    const int r = tid >> 7;
    const int jj = tid & 127;

    h_lds[r][jj] = 0.f;
    float c = 0.f;
    __syncthreads();

    for (int t = 0; t < TT; ++t) {
        if (tid < 256) {
            xt[tid >> 6][tid & 63] = x[((size_t)t * BB + b0) * II + tid];
        }
        __syncthreads();

        const int g = tid;
        float a0 = bias[g];
        float a1 = a0, a2 = a0, a3 = a0;

        #pragma unroll 4
        for (int k = 0; k < II; k += 4) {
            float4 x0 = *(const float4*)&xt[0][k];
            float4 x1 = *(const float4*)&xt[1][k];
            float4 x2 = *(const float4*)&xt[2][k];
            float4 x3 = *(const float4*)&xt[3][k];
            float w0 = WihT[(k + 0) * GG + g];
            float w1 = WihT[(k + 1) * GG + g];
            float w2 = WihT[(k + 2) * GG + g];
            float w3 = WihT[(k + 3) * GG + g];
            a0 += x0.x * w0 + x0.y * w1 + x0.z * w2 + x0.w * w3;
            a1 += x1.x * w0 + x1.y * w1 + x1.z * w2 + x1.w * w3;
            a2 += x2.x * w0 + x2.y * w1 + x2.z * w2 + x2.w * w3;
            a3 += x3.x * w0 + x3.y * w1 + x3.z * w2 + x3.w * w3;
        }
        #pragma unroll 4
        for (int k = 0; k < HH; k += 4) {
            float4 h0 = *(const float4*)&h_lds[0][k];
            float4 h1 = *(const float4*)&h_lds[1][k];
            float4 h2 = *(const float4*)&h_lds[2][k];
            float4 h3 = *(const float4*)&h_lds[3][k];
            float w0 = WhhT[(k + 0) * GG + g];
            float w1 = WhhT[(k + 1) * GG + g];
            float w2 = WhhT[(k + 2) * GG + g];
            float w3 = WhhT[(k + 3) * GG + g];
            a0 += h0.x * w0 + h0.y * w1 + h0.z * w2 + h0.w * w3;
            a1 += h1.x * w0 + h1.y * w1 + h1.z * w2 + h1.w * w3;
            a2 += h2.x * w0 + h2.y * w1 + h2.z * w2 + h2.w * w3;
            a3 += h3.x * w0 + h3.y * w1 + h3.z * w2 + h3.w * w3;
        }

        float v0, v1, v2, v3;
        if (g < 256 || g >= 384) {      // i, f, o gates: sigmoid (wave-uniform branch)
            v0 = sigmoid_f(a0); v1 = sigmoid_f(a1); v2 = sigmoid_f(a2); v3 = sigmoid_f(a3);
        } else {                        // g gate: tanh
            v0 = tanh_f(a0); v1 = tanh_f(a1); v2 = tanh_f(a2); v3 = tanh_f(a3);
        }
        gact[0][g] = v0; gact[1][g] = v1; gact[2][g] = v2; gact[3][g] = v3;
        __syncthreads();

        float iv = gact[r][jj];
        float fv = gact[r][jj + 128];
        float gv = gact[r][jj + 256];
        float ov = gact[r][jj + 384];
        c = fv * c + iv * gv;
        float hv = ov * tanh_f(c);
        h_lds[r][jj] = hv;
        hs[((size_t)t * BB + b0 + r) * HH + jj] = __float2bfloat16(hv);
        __syncthreads();
    }

    out_tail[(b0 + r) * HH + jj] = h_lds[r][jj];                 // h_n
    out_tail[BB * HH + (b0 + r) * HH + jj] = c;                  // c_n
}

// ---------- fused head MLP: out = relu(hs@W1T + b1) @ W2T + b2 ----------
__global__ __launch_bounds__(512) void head_kernel(
    const __hip_bfloat16* __restrict__ hs,
    const float* __restrict__ W1T,
    const float* __restrict__ b1,
    const float* __restrict__ W2T,
    const float* __restrict__ b2,
    float* __restrict__ out)
{
    __shared__ float h_t[HH][16];        // [k][row]
    __shared__ float o1[16][NHH + 4];    // [row][n], padded stride

    const int tid = threadIdx.x;
    const size_t row0 = (size_t)blockIdx.x * 16;

    // load 16 rows of hs (2048 bf16, contiguous) and transpose into h_t
    {
        const ushort* src = (const ushort*)(hs + row0 * HH);
        ushort4 u = ((const ushort4*)src)[tid];     // 4 elems per thread
        int idx = tid * 4;
        int row = idx >> 7;
        int k = idx & 127;
        h_t[k + 0][row] = bf2f(u.x);
        h_t[k + 1][row] = bf2f(u.y);
        h_t[k + 2][row] = bf2f(u.z);
        h_t[k + 3][row] = bf2f(u.w);
    }
    __syncthreads();

    // layer 1: 4 rows x 4 cols per thread
    {
        const int gg = tid & 127;        // col group (of 4)
        const int rr = tid >> 7;         // row group (of 4)
        const int g0 = gg * 4;
        const int r0 = rr * 4;
        float acc[4][4] = {{0.f}};
        const float4* W1T4 = (const float4*)W1T;
        for (int k = 0; k < HH; ++k) {
            float4 hv = *(const float4*)&h_t[k][r0];
            float4 wv = W1T4[k * 128 + gg];
            acc[0][0] += hv.x * wv.x; acc[0][1] += hv.x * wv.y; acc[0][2] += hv.x * wv.z; acc[0][3] += hv.x * wv.w;
            acc[1][0] += hv.y * wv.x; acc[1][1] += hv.y * wv.y; acc[1][2] += hv.y * wv.z; acc[1][3] += hv.y * wv.w;
            acc[2][0] += hv.z * wv.x; acc[2][1] += hv.z * wv.y; acc[2][2] += hv.z * wv.z; acc[2][3] += hv.z * wv.w;
            acc[3][0] += hv.w * wv.x; acc[3][1] += hv.w * wv.y; acc[3][2] += hv.w * wv.z; acc[3][3] += hv.w * wv.w;
        }
        float4 bv = ((const float4*)b1)[gg];
        float bb[4] = {bv.x, bv.y, bv.z, bv.w};
        #pragma unroll
        for (int ri = 0; ri < 4; ++ri) {
            #pragma unroll
            for (int gi = 0; gi < 4; ++gi) {
                float v = acc[ri][gi] + bb[gi];
                acc[ri][gi] = v > 0.f ? v : 0.f;
            }
            *(float4*)&o1[r0 + ri][g0] = make_float4(acc[ri][0], acc[ri][1], acc[ri][2], acc[ri][3]);
        }
    }
    __syncthreads();

    // layer 2: 16 rows x 64 cols = 1024 outputs; 256 threads x 4 cols
    if (tid < 256) {
        const int c4 = tid & 15;         // col group (of 4)
        const int r  = tid >> 4;         // row 0..15
        const int c0 = c4 * 4;
        float4 acc = make_float4(0.f, 0.f, 0.f, 0.f);
        const float4* W2T4 = (const float4*)W2T;
        for (int n = 0; n < NHH; ++n) {
            float hv = o1[r][n];
            float4 wv = W2T4[n * 16 + c4];
            acc.x += hv * wv.x; acc.y += hv * wv.y; acc.z += hv * wv.z; acc.w += hv * wv.w;
        }
        float4 bv = ((const float4*)b2)[c4];
        acc.x += bv.x; acc.y += bv.y; acc.z += bv.z; acc.w += bv.w;
        *(float4*)(out + (row0 + r) * OO + c0) = acc;
    }
}

extern "C" void kernel_launch(void* const* d_in, const int* in_sizes, int n_in,
                              void* d_out, int out_size, void* d_ws, size_t ws_size,
                              hipStream_t stream)
{
    const float* x    = (const float*)d_in[0];
    const float* W_ih = (const float*)d_in[1];
    const float* W_hh = (const float*)d_in[2];
    const float* b_ih = (const float*)d_in[3];
    const float* b_hh = (const float*)d_in[4];
    const float* W1   = (const float*)d_in[5];
    const float* b1   = (const float*)d_in[6];
    const float* W2   = (const float*)d_in[7];
    const float* b2   = (const float*)d_in[8];
    float* out = (float*)d_out;

    char* ws = (char*)d_ws;
    float* WihT = (float*)(ws + 0);          // 64*512*4   = 131072
    float* WhhT = (float*)(ws + 131072);     // 128*512*4  = 262144
    float* bias = (float*)(ws + 393216);     // 512*4      = 2048
    float* W1T  = (float*)(ws + 395264);     // 128*512*4  = 262144
    float* W2T  = (float*)(ws + 657408);     // 512*64*4   = 131072
    __hip_bfloat16* hs = (__hip_bfloat16*)(ws + 788480);   // T*B*H*2 = 134217728

    prep_kernel<<<64, 256, 0, stream>>>(W_ih, W_hh, b_ih, b_hh, W1, W2,
                                        WihT, WhhT, bias, W1T, W2T);

    lstm_scan_kernel<<<64, 512, 0, stream>>>(x, WihT, WhhT, bias, hs,
                                             out + (size_t)TT * BB * OO);

    head_kernel<<<(TT * BB) / 16, 512, 0, stream>>>(hs, W1T, b1, W2T, b2, out);
}

// Round 2
// 2566.869 us; speedup vs baseline: 6.5004x; 6.5004x over previous
//
#include <hip/hip_runtime.h>
#include <hip/hip_bf16.h>

#define TT 2048
#define BB 256
#define II 64
#define HH 128
#define GG 512   // 4*H
#define NHH 512
#define OO 64

#define HSTRIDE 132   // bf16 elems per hbuf row (128 + 4 pad; keeps b64 reads conflict-light, 8B-aligned)
#define XSTRIDE 68    // bf16 elems per xbuf row (64 + 4 pad)
#define OSTRIDE 524   // bf16 elems per o1 row in head (512 + 12 pad)

typedef short short8 __attribute__((ext_vector_type(8)));
typedef short short4v __attribute__((ext_vector_type(4)));
typedef float f32x4 __attribute__((ext_vector_type(4)));

__device__ __forceinline__ short f2bf(float f) {
    unsigned u = __float_as_uint(f);
    unsigned r = (u + 0x7fffu + ((u >> 16) & 1u)) >> 16;   // RNE
    return (short)r;
}
__device__ __forceinline__ float bf2f(short s) {
    return __uint_as_float(((unsigned)(unsigned short)s) << 16);
}
__device__ __forceinline__ float sigm(float x) {
    return __builtin_amdgcn_rcpf(1.f + __expf(-x));
}
__device__ __forceinline__ float tanh_f(float x) {
    float e = __expf(-2.f * fabsf(x));       // arg <= 0: no overflow
    float t = (1.f - e) * __builtin_amdgcn_rcpf(1.f + e);
    return copysignf(t, x);
}
// LDS-only barrier (CK idiom): waits lgkmcnt(0) but NOT vmcnt -> no HBM-store drain per step
__device__ __forceinline__ void sync_lds() {
    __builtin_amdgcn_s_waitcnt(0xC07F);
    __builtin_amdgcn_s_barrier();
}

// ---------- prep: cvt head weights to bf16 ----------
__global__ void prep_kernel(const float* __restrict__ W1, const float* __restrict__ W2,
                            short* __restrict__ W1bf, short* __restrict__ W2bf)
{
    int tid = blockIdx.x * blockDim.x + threadIdx.x;
    int n = gridDim.x * blockDim.x;
    for (int i = tid; i < NHH * HH; i += n) W1bf[i] = f2bf(W1[i]);
    for (int i = tid; i < OO * NHH; i += n) W2bf[i] = f2bf(W2[i]);
}

// ---------- LSTM scan: 64 blocks x 4 batch rows, MFMA recurrence ----------
// Weights held in VGPRs as bf16 B-fragments (48 frags = 192 VGPRs), loaded once.
// A = [h (k<128) | x (k>=128)] rows 0-3 real, rows 4-15 kept zero.
__global__ __launch_bounds__(256, 1) void lstm_scan_mfma(
    const float* __restrict__ x,
    const float* __restrict__ W_ih, const float* __restrict__ W_hh,
    const float* __restrict__ b_ih, const float* __restrict__ b_hh,
    __hip_bfloat16* __restrict__ hs,
    float* __restrict__ out_tail)
{
    __shared__ short hbuf[16 * HSTRIDE];
    __shared__ short xbuf[2][16 * XSTRIDE];
    __shared__ float gbuf[4][4][HH];    // [row 0-3][gate i,f,g,o][col]

    const int tid  = threadIdx.x;
    const int wv   = tid >> 6;          // wave 0..3
    const int lane = tid & 63;
    const int lrow = lane & 15;         // A-row / B-n / D-col index
    const int q    = lane >> 4;         // quad
    const int b0   = blockIdx.x * 4;

    for (int i = tid; i < 16 * HSTRIDE; i += 256) hbuf[i] = 0;
    for (int i = tid; i < 2 * 16 * XSTRIDE; i += 256) ((short*)xbuf)[i] = 0;

    // B fragments: B[k][n] = W[n][k]; lane holds W[n0+lrow][kt*32 + q*8 + j], j=0..7
    short8 Bf[8][6];
    float biasv[8];
    #pragma unroll
    for (int tt = 0; tt < 8; ++tt) {
        int n = (tt >> 1) * 128 + wv * 32 + (tt & 1) * 16 + lrow;   // gate*128 + wave slice
        biasv[tt] = b_ih[n] + b_hh[n];
        #pragma unroll
        for (int kt = 0; kt < 6; ++kt) {
            const float* p = (kt < 4) ? (W_hh + n * HH + kt * 32 + q * 8)
                                      : (W_ih + n * II + (kt - 4) * 32 + q * 8);
            float4 f0 = *(const float4*)p;
            float4 f1 = *(const float4*)(p + 4);
            short8 b;
            b[0] = f2bf(f0.x); b[1] = f2bf(f0.y); b[2] = f2bf(f0.z); b[3] = f2bf(f0.w);
            b[4] = f2bf(f1.x); b[5] = f2bf(f1.y); b[6] = f2bf(f1.z); b[7] = f2bf(f1.w);
            Bf[tt][kt] = b;
        }
    }

    // x staging: thread -> (row = tid>>6, col = tid&63)
    const int srow = tid >> 6;
    const int scol = tid & 63;
    {
        float x0 = x[((size_t)0 * BB + b0 + srow) * II + scol];
        xbuf[0][srow * XSTRIDE + scol] = f2bf(x0);
    }
    float xcur = x[((size_t)1 * BB + b0 + srow) * II + scol];   // for t=1
    float c0 = 0.f, c1 = 0.f;
    __syncthreads();

    for (int t = 0; t < TT; ++t) {
        // A fragments: lane reads A[lrow][kt*32 + q*8 .. +7]
        short8 Af[6];
        #pragma unroll
        for (int kt = 0; kt < 4; ++kt) {
            int off = lrow * HSTRIDE + kt * 32 + q * 8;
            union { short8 v; short4v h[2]; } u;
            u.h[0] = *(const short4v*)&hbuf[off];
            u.h[1] = *(const short4v*)&hbuf[off + 4];
            Af[kt] = u.v;
        }
        const short* xb = xbuf[t & 1];
        #pragma unroll
        for (int kt = 0; kt < 2; ++kt) {
            int off = lrow * XSTRIDE + kt * 32 + q * 8;
            union { short8 v; short4v h[2]; } u;
            u.h[0] = *(const short4v*)&xb[off];
            u.h[1] = *(const short4v*)&xb[off + 4];
            Af[4 + kt] = u.v;
        }

        float xstage = xcur;   // x_{t+1}, loaded one full iteration ago
        xcur = (t + 2 < TT) ? x[((size_t)(t + 2) * BB + b0 + srow) * II + scol] : 0.f;

        f32x4 C[8];
        #pragma unroll
        for (int tt = 0; tt < 8; ++tt) {
            f32x4 cinit = {biasv[tt], biasv[tt], biasv[tt], biasv[tt]};
            C[tt] = cinit;
        }
        #pragma unroll
        for (int kt = 0; kt < 6; ++kt) {
            #pragma unroll
            for (int tt = 0; tt < 8; ++tt)
                C[tt] = __builtin_amdgcn_mfma_f32_16x16x32_bf16(Af[kt], Bf[tt][kt], C[tt], 0, 0, 0);
        }

        // D layout: row = q*4+reg, col = lrow. Real rows 0-3 <=> q==0, row=reg.
        if (lane < 16) {
            #pragma unroll
            for (int tt = 0; tt < 8; ++tt) {
                int col = wv * 32 + (tt & 1) * 16 + lrow;
                int g = tt >> 1;
                #pragma unroll
                for (int reg = 0; reg < 4; ++reg)
                    gbuf[reg][g][col] = C[tt][reg];
            }
        }
        xbuf[(t + 1) & 1][srow * XSTRIDE + scol] = f2bf(xstage);
        sync_lds();   // #1: gbuf + next xbuf ready

        // activations: thread -> (row = wv, cols 2*lane, 2*lane+1); c persists in regs
        {
            const int row = wv;
            const int col = lane * 2;
            float2 gi = *(const float2*)&gbuf[row][0][col];
            float2 gf = *(const float2*)&gbuf[row][1][col];
            float2 gg = *(const float2*)&gbuf[row][2][col];
            float2 go = *(const float2*)&gbuf[row][3][col];
            c0 = sigm(gf.x) * c0 + sigm(gi.x) * tanh_f(gg.x);
            c1 = sigm(gf.y) * c1 + sigm(gi.y) * tanh_f(gg.y);
            float h0 = sigm(go.x) * tanh_f(c0);
            float h1 = sigm(go.y) * tanh_f(c1);
            unsigned hv = ((unsigned)(unsigned short)f2bf(h0)) |
                          (((unsigned)(unsigned short)f2bf(h1)) << 16);
            *(unsigned*)&hbuf[row * HSTRIDE + col] = hv;
            *(unsigned*)((unsigned short*)hs + ((size_t)t * BB + b0 + row) * HH + col) = hv;
        }
        sync_lds();   // #2: h_{t+1} visible for next step's A-frags
    }

    // tails: h_n (bf16-rounded, within budget) and c_n (exact fp32 path)
    {
        const int row = wv, col = lane * 2;
        out_tail[(b0 + row) * HH + col]     = bf2f(hbuf[row * HSTRIDE + col]);
        out_tail[(b0 + row) * HH + col + 1] = bf2f(hbuf[row * HSTRIDE + col + 1]);
        out_tail[BB * HH + (b0 + row) * HH + col]     = c0;
        out_tail[BB * HH + (b0 + row) * HH + col + 1] = c1;
    }
}

// ---------- fused head MLP, MFMA: out = relu(hs@W1T + b1) @ W2T + b2 ----------
// 32 rows/block; GEMM1: wave -> 128 cols; GEMM2: wave -> (16 rows, 32 cols)
__global__ __launch_bounds__(256) void head_mfma(
    const __hip_bfloat16* __restrict__ hs,
    const short* __restrict__ W1bf, const float* __restrict__ b1,
    const short* __restrict__ W2bf, const float* __restrict__ b2,
    float* __restrict__ out)
{
    __shared__ short hst[32 * HSTRIDE];
    __shared__ short o1[32 * OSTRIDE];

    const int tid  = threadIdx.x;
    const int wv   = tid >> 6;
    const int lane = tid & 63;
    const int lrow = lane & 15;
    const int q    = lane >> 4;
    const size_t rows0 = (size_t)blockIdx.x * 32;

    // stage hs tile: 32 rows x 128 bf16 (contiguous) -> LDS
    const unsigned short* src = (const unsigned short*)hs + rows0 * HH;
    for (int i = tid; i < 512; i += 256) {
        union { short8 v8; short4v h[2]; } u;
        u.v8 = *(const short8*)(src + i * 8);
        int row = (i * 8) >> 7;
        int col = (i * 8) & 127;
        *(short4v*)&hst[row * HSTRIDE + col]     = u.h[0];
        *(short4v*)&hst[row * HSTRIDE + col + 4] = u.h[1];
    }
    __syncthreads();

    // GEMM1: [32 x 128] @ [128 x 512], wave w -> cols [w*128, w*128+128)
    f32x4 C1[2][8];
    #pragma unroll
    for (int nt = 0; nt < 8; ++nt) {
        float bv = b1[wv * 128 + nt * 16 + lrow];
        f32x4 cinit = {bv, bv, bv, bv};
        C1[0][nt] = cinit;
        C1[1][nt] = cinit;
    }
    #pragma unroll
    for (int kt = 0; kt < 4; ++kt) {
        short8 Af[2];
        #pragma unroll
        for (int mt = 0; mt < 2; ++mt) {
            int off = (mt * 16 + lrow) * HSTRIDE + kt * 32 + q * 8;
            union { short8 v; short4v h[2]; } u;
            u.h[0] = *(const short4v*)&hst[off];
            u.h[1] = *(const short4v*)&hst[off + 4];
            Af[mt] = u.v;
        }
        #pragma unroll
        for (int nt = 0; nt < 8; ++nt) {
            short8 Bfr = *(const short8*)&W1bf[(wv * 128 + nt * 16 + lrow) * HH + kt * 32 + q * 8];
            C1[0][nt] = __builtin_amdgcn_mfma_f32_16x16x32_bf16(Af[0], Bfr, C1[0][nt], 0, 0, 0);
            C1[1][nt] = __builtin_amdgcn_mfma_f32_16x16x32_bf16(Af[1], Bfr, C1[1][nt], 0, 0, 0);
        }
    }
    // relu -> o1 (bf16), C-layout scatter: row = mt*16 + q*4 + reg, col = wv*128 + nt*16 + lrow
    #pragma unroll
    for (int mt = 0; mt < 2; ++mt) {
        #pragma unroll
        for (int nt = 0; nt < 8; ++nt) {
            int col = wv * 128 + nt * 16 + lrow;
            #pragma unroll
            for (int reg = 0; reg < 4; ++reg) {
                float v = C1[mt][nt][reg];
                v = v > 0.f ? v : 0.f;
                o1[(mt * 16 + q * 4 + reg) * OSTRIDE + col] = f2bf(v);
            }
        }
    }
    __syncthreads();

    // GEMM2: [32 x 512] @ [512 x 64], wave -> rows (wv&1)*16.., cols (wv>>1)*32..
    const int mt2 = wv & 1;
    const int nh  = wv >> 1;
    f32x4 C2[2];
    #pragma unroll
    for (int nt = 0; nt < 2; ++nt) {
        float bv = b2[nh * 32 + nt * 16 + lrow];
        f32x4 cinit = {bv, bv, bv, bv};
        C2[nt] = cinit;
    }
    #pragma unroll
    for (int kt = 0; kt < 16; ++kt) {
        int off = (mt2 * 16 + lrow) * OSTRIDE + kt * 32 + q * 8;
        union { short8 v; short4v h[2]; } u;
        u.h[0] = *(const short4v*)&o1[off];
        u.h[1] = *(const short4v*)&o1[off + 4];
        short8 Af = u.v;
        #pragma unroll
        for (int nt = 0; nt < 2; ++nt) {
            short8 Bfr = *(const short8*)&W2bf[(nh * 32 + nt * 16 + lrow) * NHH + kt * 32 + q * 8];
            C2[nt] = __builtin_amdgcn_mfma_f32_16x16x32_bf16(Af, Bfr, C2[nt], 0, 0, 0);
        }
    }
    #pragma unroll
    for (int nt = 0; nt < 2; ++nt) {
        #pragma unroll
        for (int reg = 0; reg < 4; ++reg)
            out[(rows0 + mt2 * 16 + q * 4 + reg) * OO + nh * 32 + nt * 16 + lrow] = C2[nt][reg];
    }
}

extern "C" void kernel_launch(void* const* d_in, const int* in_sizes, int n_in,
                              void* d_out, int out_size, void* d_ws, size_t ws_size,
                              hipStream_t stream)
{
    const float* x    = (const float*)d_in[0];
    const float* W_ih = (const float*)d_in[1];
    const float* W_hh = (const float*)d_in[2];
    const float* b_ih = (const float*)d_in[3];
    const float* b_hh = (const float*)d_in[4];
    const float* W1   = (const float*)d_in[5];
    const float* b1   = (const float*)d_in[6];
    const float* W2   = (const float*)d_in[7];
    const float* b2   = (const float*)d_in[8];
    float* out = (float*)d_out;

    char* ws = (char*)d_ws;
    short* W1bf = (short*)(ws + 0);            // 512*128*2 = 131072
    short* W2bf = (short*)(ws + 131072);       // 64*512*2  = 65536
    __hip_bfloat16* hs = (__hip_bfloat16*)(ws + 196608);   // T*B*H*2 = 134217728

    prep_kernel<<<64, 256, 0, stream>>>(W1, W2, W1bf, W2bf);

    lstm_scan_mfma<<<64, 256, 0, stream>>>(x, W_ih, W_hh, b_ih, b_hh, hs,
                                           out + (size_t)TT * BB * OO);

    head_mfma<<<(TT * BB) / 32, 256, 0, stream>>>(hs, W1bf, b1, W2bf, b2, out);
}

// Round 3
// 2540.693 us; speedup vs baseline: 6.5674x; 1.0103x over previous
//
#include <hip/hip_runtime.h>
#include <hip/hip_bf16.h>

#define TT 2048
#define BB 256
#define II 64
#define HH 128
#define GG 512   // 4*H
#define NHH 512
#define OO 64

#define HSTRIDE 132   // shorts/row: dword-stride 66 %32 = 2 -> b64 reads at conflict floor
#define XSTRIDE 68
#define OSTRIDE 516   // shorts/row: dword-stride 258 %32 = 2 -> b64 reads at conflict floor

typedef short short8 __attribute__((ext_vector_type(8)));
typedef short short4v __attribute__((ext_vector_type(4)));
typedef float f32x4 __attribute__((ext_vector_type(4)));
typedef unsigned short us4 __attribute__((ext_vector_type(4)));

__device__ __forceinline__ short f2bf(float f) {
    unsigned u = __float_as_uint(f);
    unsigned r = (u + 0x7fffu + ((u >> 16) & 1u)) >> 16;   // RNE
    return (short)r;
}
__device__ __forceinline__ float bf2f(unsigned short s) {
    return __uint_as_float(((unsigned)s) << 16);
}
__device__ __forceinline__ float sigm(float x) {
    return __builtin_amdgcn_rcpf(1.f + __expf(-x));
}
__device__ __forceinline__ float tanh_f(float x) {
    float e = __expf(-2.f * fabsf(x));
    float t = (1.f - e) * __builtin_amdgcn_rcpf(1.f + e);
    return copysignf(t, x);
}
// LDS-only barrier: waits lgkmcnt(0) but NOT vmcnt -> no HBM-store drain per step
__device__ __forceinline__ void sync_lds() {
    __builtin_amdgcn_s_waitcnt(0xC07F);
    __builtin_amdgcn_s_barrier();
}

// ---------- prep: bf16 conversions + fused bias ----------
__global__ void prep_kernel(const float* __restrict__ W_ih,
                            const float* __restrict__ b_ih, const float* __restrict__ b_hh,
                            const float* __restrict__ W1,   const float* __restrict__ W2,
                            short* __restrict__ WihBf, float* __restrict__ biasf,
                            short* __restrict__ W1bf, short* __restrict__ W2bf)
{
    int tid = blockIdx.x * blockDim.x + threadIdx.x;
    int n = gridDim.x * blockDim.x;
    for (int i = tid; i < GG * II; i += n) WihBf[i] = f2bf(W_ih[i]);
    for (int i = tid; i < GG; i += n) biasf[i] = b_ih[i] + b_hh[i];
    for (int i = tid; i < NHH * HH; i += n) W1bf[i] = f2bf(W1[i]);
    for (int i = tid; i < OO * NHH; i += n) W2bf[i] = f2bf(W2[i]);
}

// ---------- xg = x @ W_ih^T + bias, bf16 out. A=W (M=512 gates), B=x^T (N=64 rows) ----------
__global__ __launch_bounds__(256) void xg_gemm(
    const float* __restrict__ x, const short* __restrict__ WihBf,
    const float* __restrict__ biasf, unsigned short* __restrict__ xg)
{
    const int tid = threadIdx.x, wv = tid >> 6, lane = tid & 63;
    const int lrow = lane & 15, q = lane >> 4;
    const size_t rb0 = (size_t)blockIdx.x * 64;

    f32x4 C[8][4];
    #pragma unroll
    for (int mt = 0; mt < 8; ++mt) {
        float4 bv = *(const float4*)&biasf[wv * 128 + mt * 16 + q * 4];
        f32x4 ci = {bv.x, bv.y, bv.z, bv.w};
        #pragma unroll
        for (int nt = 0; nt < 4; ++nt) C[mt][nt] = ci;
    }
    #pragma unroll
    for (int kt = 0; kt < 2; ++kt) {
        short8 Bx[4];
        #pragma unroll
        for (int nt = 0; nt < 4; ++nt) {
            const float* p = x + (rb0 + nt * 16 + lrow) * II + kt * 32 + q * 8;
            float4 f0 = *(const float4*)p;
            float4 f1 = *(const float4*)(p + 4);
            short8 b;
            b[0] = f2bf(f0.x); b[1] = f2bf(f0.y); b[2] = f2bf(f0.z); b[3] = f2bf(f0.w);
            b[4] = f2bf(f1.x); b[5] = f2bf(f1.y); b[6] = f2bf(f1.z); b[7] = f2bf(f1.w);
            Bx[nt] = b;
        }
        #pragma unroll
        for (int mt = 0; mt < 8; ++mt) {
            short8 Aw = *(const short8*)&WihBf[(wv * 128 + mt * 16 + lrow) * II + kt * 32 + q * 8];
            #pragma unroll
            for (int nt = 0; nt < 4; ++nt)
                C[mt][nt] = __builtin_amdgcn_mfma_f32_16x16x32_bf16(Aw, Bx[nt], C[mt][nt], 0, 0, 0);
        }
    }
    #pragma unroll
    for (int mt = 0; mt < 8; ++mt) {
        #pragma unroll
        for (int nt = 0; nt < 4; ++nt) {
            us4 us;
            us.x = (unsigned short)f2bf(C[mt][nt][0]);
            us.y = (unsigned short)f2bf(C[mt][nt][1]);
            us.z = (unsigned short)f2bf(C[mt][nt][2]);
            us.w = (unsigned short)f2bf(C[mt][nt][3]);
            *(us4*)&xg[(rb0 + nt * 16 + lrow) * GG + wv * 128 + mt * 16 + q * 4] = us;
        }
    }
}

// ---------- LSTM scan: 64 blocks x 4 rows, 8 waves (2/SIMD), MFMA recurrence ----------
// USEXG: K=128 (h only), gate pre-acts seeded from precomputed xg. Else K=192 in-scan.
template<bool USEXG>
__global__ __launch_bounds__(512, 2) void lstm_scan5(
    const float* __restrict__ x, const unsigned short* __restrict__ xg,
    const float* __restrict__ W_ih, const float* __restrict__ W_hh,
    const float* __restrict__ b_ih, const float* __restrict__ b_hh,
    unsigned short* __restrict__ hs, float* __restrict__ out_tail)
{
    __shared__ short hbuf[16 * HSTRIDE];
    __shared__ float gbuf[4][4][HH];      // [row][gate][col]
    __shared__ short xbuf[2][16 * XSTRIDE];   // only touched when !USEXG

    const int tid  = threadIdx.x;
    const int wv   = tid >> 6;            // 8 waves
    const int lane = tid & 63;
    const int lrow = lane & 15;
    const int q    = lane >> 4;
    const int b0   = blockIdx.x * 4;

    for (int i = tid; i < 16 * HSTRIDE; i += 512) hbuf[i] = 0;
    if (!USEXG)
        for (int i = tid; i < 2 * 16 * XSTRIDE; i += 512) ((short*)xbuf)[i] = 0;

    // weight B-frags: wave owns cols [wv*64, wv*64+64) -> 4 N-tiles
    short8 Bf[4][6];
    float biasv[4];
    int colg[4];
    #pragma unroll
    for (int tt = 0; tt < 4; ++tt) {
        int n = wv * 64 + tt * 16 + lrow;
        colg[tt] = n;
        if (!USEXG) biasv[tt] = b_ih[n] + b_hh[n];
        #pragma unroll
        for (int kt = 0; kt < (USEXG ? 4 : 6); ++kt) {
            const float* p = (kt < 4) ? (W_hh + n * HH + kt * 32 + q * 8)
                                      : (W_ih + n * II + (kt - 4) * 32 + q * 8);
            float4 f0 = *(const float4*)p;
            float4 f1 = *(const float4*)(p + 4);
            short8 b;
            b[0] = f2bf(f0.x); b[1] = f2bf(f0.y); b[2] = f2bf(f0.z); b[3] = f2bf(f0.w);
            b[4] = f2bf(f1.x); b[5] = f2bf(f1.y); b[6] = f2bf(f1.z); b[7] = f2bf(f1.w);
            Bf[tt][kt] = b;
        }
    }

    // x staging (fallback path): threads <256 own (row=tid>>6, col=tid&63)
    const int srow = tid >> 6;   // only meaningful for tid<256
    const int scol = tid & 63;
    float xcur = 0.f;
    if (!USEXG && tid < 256) {
        xbuf[0][srow * XSTRIDE + scol] = f2bf(x[((size_t)0 * BB + b0 + srow) * II + scol]);
        xcur = x[((size_t)1 * BB + b0 + srow) * II + scol];
    }

    // xg prefetch regs (2-deep): xga=t, xgb=t+1, xgc=t+2
    unsigned short xga[4][4], xgb[4][4], xgc[4][4];
    if (USEXG) {
        #pragma unroll
        for (int tt = 0; tt < 4; ++tt)
            #pragma unroll
            for (int reg = 0; reg < 4; ++reg) {
                xga[tt][reg] = xg[((size_t)0 * BB + b0 + reg) * GG + colg[tt]];
                xgb[tt][reg] = xg[((size_t)1 * BB + b0 + reg) * GG + colg[tt]];
            }
    }

    float c = 0.f;
    const int arow = tid >> 7;    // activation mapping: 512 thr <-> 4 rows x 128 cols
    const int acol = tid & 127;
    __syncthreads();

    for (int t = 0; t < TT; ++t) {
        // A-frags from LDS
        short8 Af[6];
        #pragma unroll
        for (int kt = 0; kt < 4; ++kt) {
            int off = lrow * HSTRIDE + kt * 32 + q * 8;
            union { short8 v; short4v h[2]; } u;
            u.h[0] = *(const short4v*)&hbuf[off];
            u.h[1] = *(const short4v*)&hbuf[off + 4];
            Af[kt] = u.v;
        }
        if (!USEXG) {
            const short* xb = xbuf[t & 1];
            #pragma unroll
            for (int kt = 0; kt < 2; ++kt) {
                int off = lrow * XSTRIDE + kt * 32 + q * 8;
                union { short8 v; short4v h[2]; } u;
                u.h[0] = *(const short4v*)&xb[off];
                u.h[1] = *(const short4v*)&xb[off + 4];
                Af[4 + kt] = u.v;
            }
        }

        // prefetch xg for t+2 (latency covered by ~2 steps)
        if (USEXG && (t + 2 < TT)) {
            #pragma unroll
            for (int tt = 0; tt < 4; ++tt)
                #pragma unroll
                for (int reg = 0; reg < 4; ++reg)
                    xgc[tt][reg] = xg[((size_t)(t + 2) * BB + b0 + reg) * GG + colg[tt]];
        }
        float xstage = 0.f;
        if (!USEXG) {
            xstage = xcur;
            if (tid < 256)
                xcur = (t + 2 < TT) ? x[((size_t)(t + 2) * BB + b0 + srow) * II + scol] : 0.f;
        }

        // C-init: xg (rows 0-3 real; q>0 rows garbage, ignored) or bias broadcast
        f32x4 C[4];
        #pragma unroll
        for (int tt = 0; tt < 4; ++tt) {
            if (USEXG) {
                f32x4 ci = {bf2f(xga[tt][0]), bf2f(xga[tt][1]), bf2f(xga[tt][2]), bf2f(xga[tt][3])};
                C[tt] = ci;
            } else {
                f32x4 ci = {biasv[tt], biasv[tt], biasv[tt], biasv[tt]};
                C[tt] = ci;
            }
        }
        #pragma unroll
        for (int kt = 0; kt < (USEXG ? 4 : 6); ++kt)
            #pragma unroll
            for (int tt = 0; tt < 4; ++tt)
                C[tt] = __builtin_amdgcn_mfma_f32_16x16x32_bf16(Af[kt], Bf[tt][kt], C[tt], 0, 0, 0);

        // D scatter: lanes 0-15 (q==0) hold real rows 0-3 at reg index
        if (lane < 16) {
            #pragma unroll
            for (int tt = 0; tt < 4; ++tt) {
                int cg = colg[tt];
                int g = cg >> 7, cc = cg & 127;
                #pragma unroll
                for (int reg = 0; reg < 4; ++reg)
                    gbuf[reg][g][cc] = C[tt][reg];
            }
        }
        if (!USEXG && tid < 256)
            xbuf[(t + 1) & 1][srow * XSTRIDE + scol] = f2bf(xstage);
        sync_lds();   // #1: gbuf (+xbuf) ready

        // activations: one (row,col) per thread, c in reg
        {
            float gi = gbuf[arow][0][acol];
            float gf = gbuf[arow][1][acol];
            float gg = gbuf[arow][2][acol];
            float go = gbuf[arow][3][acol];
            c = sigm(gf) * c + sigm(gi) * tanh_f(gg);
            float h = sigm(go) * tanh_f(c);
            unsigned short hb = (unsigned short)f2bf(h);
            hbuf[arow * HSTRIDE + acol] = (short)hb;
            hs[((size_t)t * BB + b0 + arow) * HH + acol] = hb;
        }
        if (USEXG) {
            #pragma unroll
            for (int tt = 0; tt < 4; ++tt)
                #pragma unroll
                for (int reg = 0; reg < 4; ++reg) {
                    xga[tt][reg] = xgb[tt][reg];
                    xgb[tt][reg] = xgc[tt][reg];
                }
        }
        sync_lds();   // #2: h_{t+1} visible
    }

    out_tail[(b0 + arow) * HH + acol] = bf2f((unsigned short)hbuf[arow * HSTRIDE + acol]);
    out_tail[BB * HH + (b0 + arow) * HH + acol] = c;
}

// ---------- fused head MLP, 8 waves, direct-global A-frags ----------
__global__ __launch_bounds__(512) void head_mfma(
    const unsigned short* __restrict__ hs,
    const short* __restrict__ W1bf, const float* __restrict__ b1,
    const short* __restrict__ W2bf, const float* __restrict__ b2,
    float* __restrict__ out)
{
    __shared__ short o1[32 * OSTRIDE];

    const int tid = threadIdx.x, wv = tid >> 6, lane = tid & 63;
    const int lrow = lane & 15, q = lane >> 4;
    const size_t rows0 = (size_t)blockIdx.x * 32;

    // GEMM1: wave -> (mt = wv&1 row-half, nb = (wv>>1)*128 col slice)
    const int mt = wv & 1;
    const int nb = (wv >> 1) * 128;
    f32x4 C1[8];
    #pragma unroll
    for (int nt = 0; nt < 8; ++nt) {
        float bv = b1[nb + nt * 16 + lrow];
        f32x4 ci = {bv, bv, bv, bv};
        C1[nt] = ci;
    }
    #pragma unroll
    for (int kt = 0; kt < 4; ++kt) {
        short8 Af = *(const short8*)(hs + (rows0 + mt * 16 + lrow) * HH + kt * 32 + q * 8);
        #pragma unroll
        for (int nt = 0; nt < 8; ++nt) {
            short8 Bfr = *(const short8*)&W1bf[(nb + nt * 16 + lrow) * HH + kt * 32 + q * 8];
            C1[nt] = __builtin_amdgcn_mfma_f32_16x16x32_bf16(Af, Bfr, C1[nt], 0, 0, 0);
        }
    }
    #pragma unroll
    for (int nt = 0; nt < 8; ++nt) {
        #pragma unroll
        for (int reg = 0; reg < 4; ++reg) {
            float v = C1[nt][reg];
            v = v > 0.f ? v : 0.f;
            o1[(mt * 16 + q * 4 + reg) * OSTRIDE + nb + nt * 16 + lrow] = f2bf(v);
        }
    }
    __syncthreads();

    // GEMM2: wave -> (mt2 row-half, nh = wv>>1 col tile of 16)
    const int mt2 = wv & 1;
    const int nh  = wv >> 1;
    f32x4 C2;
    {
        float bv = b2[nh * 16 + lrow];
        f32x4 ci = {bv, bv, bv, bv};
        C2 = ci;
    }
    #pragma unroll
    for (int kt = 0; kt < 16; ++kt) {
        int off = (mt2 * 16 + lrow) * OSTRIDE + kt * 32 + q * 8;
        union { short8 v; short4v h[2]; } u;
        u.h[0] = *(const short4v*)&o1[off];
        u.h[1] = *(const short4v*)&o1[off + 4];
        short8 Bfr = *(const short8*)&W2bf[(nh * 16 + lrow) * NHH + kt * 32 + q * 8];
        C2 = __builtin_amdgcn_mfma_f32_16x16x32_bf16(u.v, Bfr, C2, 0, 0, 0);
    }
    #pragma unroll
    for (int reg = 0; reg < 4; ++reg)
        out[(rows0 + mt2 * 16 + q * 4 + reg) * OO + nh * 16 + lrow] = C2[reg];
}

extern "C" void kernel_launch(void* const* d_in, const int* in_sizes, int n_in,
                              void* d_out, int out_size, void* d_ws, size_t ws_size,
                              hipStream_t stream)
{
    const float* x    = (const float*)d_in[0];
    const float* W_ih = (const float*)d_in[1];
    const float* W_hh = (const float*)d_in[2];
    const float* b_ih = (const float*)d_in[3];
    const float* b_hh = (const float*)d_in[4];
    const float* W1   = (const float*)d_in[5];
    const float* b1   = (const float*)d_in[6];
    const float* W2   = (const float*)d_in[7];
    const float* b2   = (const float*)d_in[8];
    float* out = (float*)d_out;

    char* ws = (char*)d_ws;
    short* W1bf  = (short*)(ws + 0);                       // 131072
    short* W2bf  = (short*)(ws + 131072);                  // 65536
    short* WihBf = (short*)(ws + 196608);                  // 65536
    float* biasf = (float*)(ws + 262144);                  // 2048
    unsigned short* hs = (unsigned short*)(ws + 264192);   // 134217728
    unsigned short* xgbuf = (unsigned short*)(ws + 134481920);  // 536870912

    const bool fast = ws_size >= 671352832ULL;   // constant per session -> graph-safe

    prep_kernel<<<64, 256, 0, stream>>>(W_ih, b_ih, b_hh, W1, W2, WihBf, biasf, W1bf, W2bf);

    float* tail = out + (size_t)TT * BB * OO;
    if (fast) {
        xg_gemm<<<(TT * BB) / 64, 256, 0, stream>>>(x, WihBf, biasf, xgbuf);
        lstm_scan5<true><<<64, 512, 0, stream>>>(x, xgbuf, W_ih, W_hh, b_ih, b_hh, hs, tail);
    } else {
        lstm_scan5<false><<<64, 512, 0, stream>>>(x, nullptr, W_ih, W_hh, b_ih, b_hh, hs, tail);
    }

    head_mfma<<<(TT * BB) / 32, 512, 0, stream>>>(hs, W1bf, b1, W2bf, b2, out);
}